// Round 3
// baseline (201.948 us; speedup 1.0000x reference)
//
#include <hip/hip_runtime.h>

// loss = sum_i ( -2*logits[i, t_i] + top1_i + top2_i )
// (log_softmax's lse cancels exactly: -2(x_t - lse) + (m1 - lse) + (m2 - lse)
//  = m1 + m2 - 2 x_t, since CONTRASTIVE_NUM == 2 == broadcast count)
// Harness delivers integer inputs as int32.

#define NROWS 8192
#define VOCAB 32000
#define ROWS_PER_BLOCK 4   // one 64-lane wave per row; no LDS, no barriers

typedef float floatx4 __attribute__((ext_vector_type(4)));

__global__ __launch_bounds__(256) void cce_kernel(const float* __restrict__ logits,
                                                  const int* __restrict__ target,
                                                  float* __restrict__ out) {
    const int wave = threadIdx.x >> 6;
    const int lane = threadIdx.x & 63;
    const int row  = blockIdx.x * ROWS_PER_BLOCK + wave;

    const floatx4* rp = reinterpret_cast<const floatx4*>(logits + (size_t)row * VOCAB);

    // Issue the target gather early (lane 0 only); latency hides under the stream.
    float tv = 0.0f;
    if (lane == 0) {
        const int t = target[row];
        tv = logits[(size_t)row * VOCAB + (size_t)t];
    }

    // 8000 float4 per row / 64 lanes = exactly 125 iterations per lane.
    float m1 = -INFINITY, m2 = -INFINITY;
    #pragma unroll 5
    for (int i = lane; i < VOCAB / 4; i += 64) {
        floatx4 v = __builtin_nontemporal_load(&rp[i]);  // streaming, zero reuse
        m2 = fmaxf(m2, fminf(m1, v.x)); m1 = fmaxf(m1, v.x);
        m2 = fmaxf(m2, fminf(m1, v.y)); m1 = fmaxf(m1, v.y);
        m2 = fmaxf(m2, fminf(m1, v.z)); m1 = fmaxf(m1, v.z);
        m2 = fmaxf(m2, fminf(m1, v.w)); m1 = fmaxf(m1, v.w);
    }

    // 64-lane butterfly reduction of the (m1, m2) pair
    #pragma unroll
    for (int off = 32; off > 0; off >>= 1) {
        float o1 = __shfl_xor(m1, off, 64);
        float o2 = __shfl_xor(m2, off, 64);
        float nm1 = fmaxf(m1, o1);
        float nm2 = fmaxf(fminf(m1, o1), fmaxf(m2, o2));
        m1 = nm1; m2 = nm2;
    }

    if (lane == 0) {
        atomicAdd(out, m1 + m2 - 2.0f * tv);   // one atomic per wave, time-spread
    }
}

extern "C" void kernel_launch(void* const* d_in, const int* in_sizes, int n_in,
                              void* d_out, int out_size, void* d_ws, size_t ws_size,
                              hipStream_t stream) {
    const float* logits = (const float*)d_in[0];
    const int* target = (const int*)d_in[1];
    float* out = (float*)d_out;

    // Atomics accumulate into d_out: must zero it every call (graph-safe memset node).
    hipMemsetAsync(out, 0, sizeof(float), stream);
    cce_kernel<<<NROWS / ROWS_PER_BLOCK, 256, 0, stream>>>(logits, target, out);
}